// Round 15
// baseline (6064.821 us; speedup 1.0000x reference)
//
#include <hip/hip_runtime.h>

#define T_LEN 16384
#define BATCH 32
#define HID 32
#define L2E 1.44269504088896340736f
#define SCLG (-2.0f * 1.44269504088896340736f)   // -2*log2e

typedef float f2 __attribute__((ext_vector_type(2)));
typedef unsigned u2_t __attribute__((ext_vector_type(2)));

#if __has_builtin(__builtin_amdgcn_exp2f)
#define EXP2F(x) __builtin_amdgcn_exp2f(x)
#else
#define EXP2F(x) __exp2f(x)
#endif
#if __has_builtin(__builtin_amdgcn_rcpf)
#define RCPF(x) __builtin_amdgcn_rcpf(x)
#else
#define RCPF(x) (1.0f / (x))
#endif

__device__ __forceinline__ float rlane(float v, int lane) {
    return __int_as_float(__builtin_amdgcn_readlane(__float_as_int(v), lane));
}

// Cross-half exchange (lower->upper), VALU pipe. Convention verified r4/r5:
// builtin returns {vdst_new, vsrc_new}; r.x has lanes 32-63 = old lanes 0-31.
__device__ __forceinline__ float xhalf_lo_to_hi(float v) {
#if __has_builtin(__builtin_amdgcn_permlane32_swap)
    u2_t r = __builtin_amdgcn_permlane32_swap(__float_as_uint(v), __float_as_uint(v),
                                              false, false);
    return __uint_as_float(r.x);
#else
    return __shfl_xor(v, 32, 64);
#endif
}

// r15 = r14 (3069us, 450 cyc/step) + three chain/issue trims:
//  1. hbuf merged into phist: phist stores RAW h; step s's broadcast reads
//     row s-1 (wave-uniform). Deletes 1 ds_write + the h*wout mul per step;
//     flush applies W_out via per-lane wv[] fmas (same op count, off-chain).
//     Chunk boundary: s=0 reads row 63 = previous chunk's last h; seeded 0.
//  2. xpA/xpB folded into split-accumulator 0's init ({xp,0} + pk_fma):
//     -2 dependent adds at dot exit, +2 off-chain movs.
//  3. lower-half B-shaping folded with SCLG: tgS = fma(r, 2SCLG, -SCLG),
//     up = A*tgS (one less dependent mul pre-ship); upper uses r as so.
__global__ __launch_bounds__(64) __attribute__((amdgpu_waves_per_eu(1, 1)))
void lstm_seq_kernel(const float* __restrict__ x,
                     const float* __restrict__ W_ih,
                     const float* __restrict__ W_hh,
                     const float* __restrict__ b_ih,
                     const float* __restrict__ b_hh,
                     const float* __restrict__ W_out,
                     const float* __restrict__ b_out,
                     float* __restrict__ out)
{
    const int b    = blockIdx.x;
    const int lane = threadIdx.x;
    const int j    = lane & 31;
    const bool upper = (lane >= 32);

    // torch gate order in W_ih/W_hh rows: [0,32)=i [32,64)=f [64,96)=g [96,128)=o
    const int rowA = upper ? (32 + j) : j;        // f : i   (both sigmoid)
    const int rowB = upper ? (96 + j) : (64 + j); // o : g   (sigmoid : tanh)

    // Pre-scale: sigmoid rows by -L2E; tanh row (g, lower B) by -2*L2E.
    const float sclA = -L2E;
    const float sclB = upper ? -L2E : SCLG;

    // W rows as float2 pairs (pre-scaled), pinned resident (r9/r12)
    f2 Wa2[16], Wb2[16];
    const f2* ra2 = reinterpret_cast<const f2*>(W_hh + (size_t)rowA * HID);
    const f2* rb2 = reinterpret_cast<const f2*>(W_hh + (size_t)rowB * HID);
    #pragma unroll
    for (int q = 0; q < 16; ++q) { Wa2[q] = ra2[q] * sclA; Wb2[q] = rb2[q] * sclB; }
    #pragma unroll
    for (int q = 0; q < 16; ++q) { asm("" : "+v"(Wa2[q]), "+v"(Wb2[q])); }

    const float wihA = sclA * W_ih[rowA];
    const float wihB = sclB * W_ih[rowB];
    const float bA = sclA * (b_ih[rowA] + b_hh[rowA]);
    const float bB = sclB * (b_ih[rowB] + b_hh[rowB]);

    const float bout = b_out[0];
    // flush weight vector: every lane holds all 32 W_out entries
    float wv[HID];
    #pragma unroll
    for (int k = 0; k < HID; ++k) wv[k] = W_out[k];

    // phist[s][lane], stride 65: row s holds RAW h (upper columns 32..63
    // valid). Doubles as the h-broadcast buffer: step s reads row s-1.
    __shared__ float phist[64 * 65];

    float cS = 0.0f;             // cS = -2log2e * c, state in upper lanes
    phist[63 * 65 + lane] = 0.0f;  // seed h_{-1} = 0 (read by step 0)
    __syncthreads();

    const float* xb = x + (size_t)b * T_LEN;
    float*       yb = out + (size_t)b * T_LEN;

    float xv = xb[lane];  // 64 timesteps of x per lane-chunk

    for (int t0 = 0; t0 < T_LEN; t0 += 64) {
        float xv_next = (t0 + 64 < T_LEN) ? xb[t0 + 64 + lane] : 0.0f;

        #pragma unroll 4
        for (int s = 0; s < 64; ++s) {
            // x contribution: independent of h, schedules off-chain
            const float xs  = rlane(xv, s);
            const float xpA = fmaf(xs, wihA, bA);
            const float xpB = fmaf(xs, wihB, bB);

            // broadcast read of h_{s-1}: row (s-1+64)%64, wave-uniform,
            // conflict-free, 16 f2 loads landing as aligned VGPR pairs.
            const int prow = (s + 63) & 63;
            const f2* hb2 = reinterpret_cast<const f2*>(&phist[prow * 65 + 32]);
            f2 hv2[16];
            #pragma unroll
            for (int p = 0; p < 16; ++p) hv2[p] = hb2[p];

            // dots: 32 pure-VGPR v_pk_fma_f32, 4-way split accumulators;
            // accumulator 0 starts at {xp, 0} (folds the x/bias term).
            f2 zA[4], zB[4];
            zA[0].x = xpA; zA[0].y = 0.0f;
            zB[0].x = xpB; zB[0].y = 0.0f;
            #pragma unroll
            for (int p = 0; p < 16; ++p) {
                if (p == 0) {
                    asm("v_pk_fma_f32 %0, %1, %2, %0"
                        : "+v"(zA[0]) : "v"(hv2[0]), "v"(Wa2[0]));
                    asm("v_pk_fma_f32 %0, %1, %2, %0"
                        : "+v"(zB[0]) : "v"(hv2[0]), "v"(Wb2[0]));
                } else if (p < 4) {
                    asm("v_pk_mul_f32 %0, %1, %2"
                        : "=v"(zA[p]) : "v"(hv2[p]), "v"(Wa2[p]));
                    asm("v_pk_mul_f32 %0, %1, %2"
                        : "=v"(zB[p]) : "v"(hv2[p]), "v"(Wb2[p]));
                } else {
                    asm("v_pk_fma_f32 %0, %1, %2, %0"
                        : "+v"(zA[p & 3]) : "v"(hv2[p]), "v"(Wa2[p]));
                    asm("v_pk_fma_f32 %0, %1, %2, %0"
                        : "+v"(zB[p & 3]) : "v"(hv2[p]), "v"(Wb2[p]));
                }
            }
            const f2 rA = (zA[0] + zA[1]) + (zA[2] + zA[3]);
            const f2 rB = (zB[0] + zB[1]) + (zB[2] + zB[3]);
            const float za = rA.x + rA.y;   // pre-scaled gate input
            const float zb = rB.x + rB.y;

            // A = sigmoid (i lower / f upper): rcp(1+exp2(za))
            const float A = RCPF(1.0f + EXP2F(za));
            const float r = RCPF(1.0f + EXP2F(zb));
            // lower: tgS = -2log2e*tanh(g) = fma(r, 2SCLG, -SCLG)
            const float tgS = fmaf(r, 2.0f * SCLG, -SCLG);
            const float so2 = r + r;               // 2*so (upper), off-chain

            // lower: u' = A * tgS = -2log2e*(si*tg); ship to upper
            const float up = A * tgS;
            const float tu = xhalf_lo_to_hi(up);

            // upper: cS = sf*cS + u'; tanh(c) via exp2(cS) direct
            cS = fmaf(A, cS, tu);
            const float r2 = RCPF(1.0f + EXP2F(cS));
            const float h  = fmaf(so2, r2, -r);    // so*tanh(c)

            phist[s * 65 + lane] = h;   // publish raw h (dot + flush source)
        }

        __syncthreads();  // single wave: cheap; publish phist
        float acc = bout;
        #pragma unroll
        for (int k = 0; k < HID; ++k)
            acc = fmaf(phist[lane * 65 + 32 + k], wv[k], acc);
        yb[t0 + lane] = acc;
        __syncthreads();  // protect phist before next chunk rewrites it

        xv = xv_next;
    }
}

extern "C" void kernel_launch(void* const* d_in, const int* in_sizes, int n_in,
                              void* d_out, int out_size, void* d_ws, size_t ws_size,
                              hipStream_t stream) {
    const float* x     = (const float*)d_in[0];
    const float* W_ih  = (const float*)d_in[1];
    const float* W_hh  = (const float*)d_in[2];
    const float* b_ih  = (const float*)d_in[3];
    const float* b_hh  = (const float*)d_in[4];
    const float* W_out = (const float*)d_in[5];
    const float* b_out = (const float*)d_in[6];
    float* out = (float*)d_out;

    lstm_seq_kernel<<<BATCH, 64, 0, stream>>>(x, W_ih, W_hh, b_ih, b_hh,
                                              W_out, b_out, out);
}

// Round 16
// 3062.764 us; speedup vs baseline: 1.9802x; 1.9802x over previous
//
#include <hip/hip_runtime.h>

#define T_LEN 16384
#define BATCH 32
#define HID 32
#define L2E 1.44269504088896340736f
#define SCLG (-2.0f * 1.44269504088896340736f)   // -2*log2e

typedef float f2 __attribute__((ext_vector_type(2)));
typedef unsigned u2_t __attribute__((ext_vector_type(2)));

#if __has_builtin(__builtin_amdgcn_exp2f)
#define EXP2F(x) __builtin_amdgcn_exp2f(x)
#else
#define EXP2F(x) __exp2f(x)
#endif
#if __has_builtin(__builtin_amdgcn_rcpf)
#define RCPF(x) __builtin_amdgcn_rcpf(x)
#else
#define RCPF(x) (1.0f / (x))
#endif

__device__ __forceinline__ float rlane(float v, int lane) {
    return __int_as_float(__builtin_amdgcn_readlane(__float_as_int(v), lane));
}

// Cross-half exchange (lower->upper), VALU pipe. Convention verified r4/r5:
// builtin returns {vdst_new, vsrc_new}; r.x has lanes 32-63 = old lanes 0-31.
__device__ __forceinline__ float xhalf_lo_to_hi(float v) {
#if __has_builtin(__builtin_amdgcn_permlane32_swap)
    u2_t r = __builtin_amdgcn_permlane32_swap(__float_as_uint(v), __float_as_uint(v),
                                              false, false);
    return __uint_as_float(r.x);
#else
    return __shfl_xor(v, 32, 64);
#endif
}

// r16 = r14 (3069us) + the two UNCONFOUNDED trims from r15.
// r15 lesson (6065us, VALUBusy halved): merging the h-broadcast into the
// row-varying phist kills the compiler's alias analysis — broadcast reads
// conservatively wait on all scatter stores (lgkmcnt(0) per step) and
// cross-iteration pipelining dies. hbuf MUST stay a separate fixed-address
// buffer with a single writer. Kept trims:
//  2. x/bias folded into split-accumulator 0 init ({xp,0}): -2 dependent
//     adds at dot exit.
//  3. tgS = fma(r, 2SCLG, -SCLG); up = A*tgS (one less dependent mul on the
//     lower pre-ship path); upper uses r directly: h = fma(r+r, r2, -r).
__global__ __launch_bounds__(64) __attribute__((amdgpu_waves_per_eu(1, 1)))
void lstm_seq_kernel(const float* __restrict__ x,
                     const float* __restrict__ W_ih,
                     const float* __restrict__ W_hh,
                     const float* __restrict__ b_ih,
                     const float* __restrict__ b_hh,
                     const float* __restrict__ W_out,
                     const float* __restrict__ b_out,
                     float* __restrict__ out)
{
    const int b    = blockIdx.x;
    const int lane = threadIdx.x;
    const int j    = lane & 31;
    const bool upper = (lane >= 32);

    // torch gate order in W_ih/W_hh rows: [0,32)=i [32,64)=f [64,96)=g [96,128)=o
    const int rowA = upper ? (32 + j) : j;        // f : i   (both sigmoid)
    const int rowB = upper ? (96 + j) : (64 + j); // o : g   (sigmoid : tanh)

    // Pre-scale: sigmoid rows by -L2E; tanh row (g, lower B) by -2*L2E.
    const float sclA = -L2E;
    const float sclB = upper ? -L2E : SCLG;

    // W rows as float2 pairs (pre-scaled), pinned resident (r9/r12)
    f2 Wa2[16], Wb2[16];
    const f2* ra2 = reinterpret_cast<const f2*>(W_hh + (size_t)rowA * HID);
    const f2* rb2 = reinterpret_cast<const f2*>(W_hh + (size_t)rowB * HID);
    #pragma unroll
    for (int q = 0; q < 16; ++q) { Wa2[q] = ra2[q] * sclA; Wb2[q] = rb2[q] * sclB; }
    #pragma unroll
    for (int q = 0; q < 16; ++q) { asm("" : "+v"(Wa2[q]), "+v"(Wb2[q])); }

    const float wihA = sclA * W_ih[rowA];
    const float wihB = sclB * W_ih[rowB];
    const float bA = sclA * (b_ih[rowA] + b_hh[rowA]);
    const float bB = sclB * (b_ih[rowB] + b_hh[rowB]);

    const float wout = W_out[j];
    const float bout = b_out[0];

    // phist[s][lane], stride 65: store banks (s+l)%32 conflict-free;
    // flush read phist[l*65+32+k] banks (l+k)%32 conflict-free.
    __shared__ float phist[64 * 65];
    // h-broadcast buffer: FIXED address, single writer per slot (see r15
    // lesson above) — slot per lane; upper 32 slots [32..63] hold h_j.
    __shared__ float hbuf[64];

    float cS = 0.0f;             // cS = -2log2e * c, state in upper lanes
    hbuf[lane] = 0.0f;           // seed h_0 = 0
    __syncthreads();

    const float* xb = x + (size_t)b * T_LEN;
    float*       yb = out + (size_t)b * T_LEN;
    // wave-uniform broadcast-read base (h values live at hbuf[32..63]),
    // read as f2 pairs -> register pairs that ARE the pk_fma operands.
    const f2* hb2 = reinterpret_cast<const f2*>(&hbuf[32]);

    float xv = xb[lane];  // 64 timesteps of x per lane-chunk

    for (int t0 = 0; t0 < T_LEN; t0 += 64) {
        float xv_next = (t0 + 64 < T_LEN) ? xb[t0 + 64 + lane] : 0.0f;

        #pragma unroll 4
        for (int s = 0; s < 64; ++s) {
            // x contribution: independent of h, schedules off-chain
            const float xs  = rlane(xv, s);
            const float xpA = fmaf(xs, wihA, bA);
            const float xpB = fmaf(xs, wihB, bB);

            // broadcast read: 16 f2 loads, wave-uniform, conflict-free,
            // pipelined; each lands as an even-aligned VGPR pair.
            f2 hv2[16];
            #pragma unroll
            for (int p = 0; p < 16; ++p) hv2[p] = hb2[p];

            // dots: 32 pure-VGPR v_pk_fma_f32, 4-way split accumulators;
            // accumulator 0 starts at {xp, 0} (x/bias folded in).
            f2 zA[4], zB[4];
            zA[0].x = xpA; zA[0].y = 0.0f;
            zB[0].x = xpB; zB[0].y = 0.0f;
            #pragma unroll
            for (int p = 0; p < 16; ++p) {
                if (p == 0) {
                    asm("v_pk_fma_f32 %0, %1, %2, %0"
                        : "+v"(zA[0]) : "v"(hv2[0]), "v"(Wa2[0]));
                    asm("v_pk_fma_f32 %0, %1, %2, %0"
                        : "+v"(zB[0]) : "v"(hv2[0]), "v"(Wb2[0]));
                } else if (p < 4) {
                    asm("v_pk_mul_f32 %0, %1, %2"
                        : "=v"(zA[p]) : "v"(hv2[p]), "v"(Wa2[p]));
                    asm("v_pk_mul_f32 %0, %1, %2"
                        : "=v"(zB[p]) : "v"(hv2[p]), "v"(Wb2[p]));
                } else {
                    asm("v_pk_fma_f32 %0, %1, %2, %0"
                        : "+v"(zA[p & 3]) : "v"(hv2[p]), "v"(Wa2[p]));
                    asm("v_pk_fma_f32 %0, %1, %2, %0"
                        : "+v"(zB[p & 3]) : "v"(hv2[p]), "v"(Wb2[p]));
                }
            }
            const f2 rA = (zA[0] + zA[1]) + (zA[2] + zA[3]);
            const f2 rB = (zB[0] + zB[1]) + (zB[2] + zB[3]);
            const float za = rA.x + rA.y;   // pre-scaled gate input
            const float zb = rB.x + rB.y;

            // A = sigmoid (i lower / f upper): rcp(1+exp2(za))
            const float A = RCPF(1.0f + EXP2F(za));
            const float r = RCPF(1.0f + EXP2F(zb));
            // lower: tgS = -2log2e*tanh(g) = fma(r, 2SCLG, -SCLG)
            const float tgS = fmaf(r, 2.0f * SCLG, -SCLG);
            const float so2 = r + r;               // 2*so (upper), off-chain

            // lower: u' = A*tgS = -2log2e*(si*tg); ship to upper (VALU swap)
            const float up = A * tgS;
            const float tu = xhalf_lo_to_hi(up);

            // upper: cS = sf*cS + u'; tanh(c) via exp2(cS) direct
            cS = fmaf(A, cS, tu);
            const float r2 = RCPF(1.0f + EXP2F(cS));
            const float h  = fmaf(so2, r2, -r);    // so*tanh(c)

            hbuf[lane] = h;                    // publish FIRST (gates next step)
            phist[s * 65 + lane] = h * wout;   // deferred output (off-chain)
        }

        __syncthreads();  // single wave: cheap; publish phist
        float acc = bout;
        #pragma unroll
        for (int k = 0; k < HID; ++k) acc += phist[lane * 65 + 32 + k];
        yb[t0 + lane] = acc;
        __syncthreads();  // protect phist before next chunk rewrites it

        xv = xv_next;
    }
}

extern "C" void kernel_launch(void* const* d_in, const int* in_sizes, int n_in,
                              void* d_out, int out_size, void* d_ws, size_t ws_size,
                              hipStream_t stream) {
    const float* x     = (const float*)d_in[0];
    const float* W_ih  = (const float*)d_in[1];
    const float* W_hh  = (const float*)d_in[2];
    const float* b_ih  = (const float*)d_in[3];
    const float* b_hh  = (const float*)d_in[4];
    const float* W_out = (const float*)d_in[5];
    const float* b_out = (const float*)d_in[6];
    float* out = (float*)d_out;

    lstm_seq_kernel<<<BATCH, 64, 0, stream>>>(x, W_ih, W_hh, b_ih, b_hh,
                                              W_out, b_out, out);
}